// Round 8
// baseline (320.027 us; speedup 1.0000x reference)
//
#include <hip/hip_runtime.h>

// Linear RNN scan: h_t = h_{t-1}@A + x_t@B ; y_t = h_t@C
// B=8, S=4096, IN=STATE=OUT=256.
// MFMA 16x16x32 f16, 2-term split (hi + 2048*lo), f32 accumulate.
// Swapped operands: out^T = M^T @ in^T (resident frags = A-operand, LDS tile = B-operand).
// Slice-linear LDS: per slice s a 1024B region, slot ((ak<<4)|row)^s -> conflict-free.
// FUSED sweeps:
//   scan_up   = (u = x@B) + chunk local scan (writes U, E)      512 chunks/2 = 256 blocks
//   scan_down = chunk scan from entry + (y = h@C)               256 blocks
// Spine: collect (A^8) / top (A^128) / scan2 (A^8) on mfma_rscan.

#define SEQ    4096
#define NBATCH 8
#define ND     256
#define CHUNK  8
#define NCHUNK 512
#define GSZ    16
#define NGRP   32
#define LOSC   2048.0f
#define LOINV  (1.0f/2048.0f)

typedef _Float16 fp16_t;
typedef __attribute__((ext_vector_type(8))) _Float16 f16x8;
typedef __attribute__((ext_vector_type(4))) _Float16 f16x4;
typedef __attribute__((ext_vector_type(4))) float f32x4;

// ---------- pack A,B,C into frag arrays (hi/lo f16) ----------
// frag linear index: ((tile*8 + slice)*64 + lane)*8 + j
// value = M[k][n], k = slice*32 + (lane>>4)*8 + j, n = tile*16 + (lane&15)
__global__ __launch_bounds__(64) void prep_frags3(
    const float* __restrict__ A, const float* __restrict__ B,
    const float* __restrict__ C,
    fp16_t* __restrict__ fAh, fp16_t* __restrict__ fAl,
    fp16_t* __restrict__ fBh, fp16_t* __restrict__ fBl,
    fp16_t* __restrict__ fCh, fp16_t* __restrict__ fCl) {
  const int which = blockIdx.x >> 7;
  const int blk   = blockIdx.x & 127;
  const float* M = (which == 0) ? A : (which == 1) ? B : C;
  fp16_t* hi = (which == 0) ? fAh : (which == 1) ? fBh : fCh;
  fp16_t* lo = (which == 0) ? fAl : (which == 1) ? fBl : fCl;
  const int lane = threadIdx.x;
  const int tile = blk >> 3, slice = blk & 7;
  const int n  = tile * 16 + (lane & 15);
  const int k0 = slice * 32 + (lane >> 4) * 8;
  f16x8 vh, vl;
  #pragma unroll
  for (int j = 0; j < 8; ++j) {
    const float v = M[(size_t)(k0 + j) * ND + n];
    const fp16_t h = (fp16_t)v;
    vh[j] = h;
    vl[j] = (fp16_t)((v - (float)h) * LOSC);
  }
  const size_t fo = ((size_t)blk * 64 + lane) * 8;
  *(f16x8*)&hi[fo] = vh;
  *(f16x8*)&lo[fo] = vl;
}

// ---------- pack A8, A128 into frag arrays ----------
__global__ __launch_bounds__(64) void prep_frags2(
    const float* __restrict__ M0, const float* __restrict__ M1,
    fp16_t* __restrict__ h0p, fp16_t* __restrict__ l0p,
    fp16_t* __restrict__ h1p, fp16_t* __restrict__ l1p) {
  const int which = blockIdx.x >> 7;
  const int blk   = blockIdx.x & 127;
  const float* M = (which == 0) ? M0 : M1;
  fp16_t* hi = (which == 0) ? h0p : h1p;
  fp16_t* lo = (which == 0) ? l0p : l1p;
  const int lane = threadIdx.x;
  const int tile = blk >> 3, slice = blk & 7;
  const int n  = tile * 16 + (lane & 15);
  const int k0 = slice * 32 + (lane >> 4) * 8;
  f16x8 vh, vl;
  #pragma unroll
  for (int j = 0; j < 8; ++j) {
    const float v = M[(size_t)(k0 + j) * ND + n];
    const fp16_t h = (fp16_t)v;
    vh[j] = h;
    vl[j] = (fp16_t)((v - (float)h) * LOSC);
  }
  const size_t fo = ((size_t)blk * 64 + lane) * 8;
  *(f16x8*)&hi[fo] = vh;
  *(f16x8*)&lo[fo] = vl;
}

// ---------- fused up-sweep: u = x@B on the fly; local chunk scan; writes U, E ----------
__global__ __launch_bounds__(1024, 1) void scan_up(
    const fp16_t* __restrict__ fAh, const fp16_t* __restrict__ fAl,
    const fp16_t* __restrict__ fBh, const fp16_t* __restrict__ fBl,
    const float* __restrict__ x, float* __restrict__ U, float* __restrict__ E) {
  const int c2   = blockIdx.x;        // chunks 2*c2, 2*c2+1
  const int tid  = threadIdx.x;
  const int lane = tid & 63;
  const int w    = tid >> 6;
  const int br   = lane & 15;
  const int akg  = lane >> 4;

  __shared__ fp16_t xH[2][8 * 512], xL[2][8 * 512];
  __shared__ fp16_t hH[2][8 * 512], hL[2][8 * 512];

  // staging geometry: thread loads 4 f32 of one (c,b) row per step
  const int srow  = tid >> 6;                 // 0..15
  const int scol  = (tid & 63) * 4;           // 0..252
  const int ss    = (tid >> 3) & 7;
  const int sak   = (tid >> 1) & 3;
  const int shalf = tid & 1;
  const int soff  = (ss << 10) + ((((sak << 4) | srow) ^ ss) << 4) + shalf * 8;
  const int sb    = srow & 7;
  const int sc    = 2 * c2 + (srow >> 3);
  const float* xsrc = &x[((size_t)sb * SEQ + (size_t)sc * CHUNK) * ND + scol];

  // resident frags: A^T and B^T
  f16x8 AH[8], AL[8], BH[8], BL[8];
  #pragma unroll
  for (int s = 0; s < 8; ++s) {
    const size_t fo = (((size_t)w * 8 + s) * 64 + lane) * 8;
    AH[s] = *(const f16x8*)&fAh[fo];
    AL[s] = *(const f16x8*)&fAl[fo];
    BH[s] = *(const f16x8*)&fBh[fo];
    BL[s] = *(const f16x8*)&fBl[fo];
  }

  // stage x_0 into xbuf 0
  {
    const float4 xv = *(const float4*)xsrc;
    const float a[4] = {xv.x, xv.y, xv.z, xv.w};
    f16x4 vh, vl;
    #pragma unroll
    for (int r = 0; r < 4; ++r) {
      const fp16_t h = (fp16_t)a[r];
      vh[r] = h;
      vl[r] = (fp16_t)((a[r] - (float)h) * LOSC);
    }
    *(f16x4*)((char*)xH[0] + soff) = vh;
    *(f16x4*)((char*)xL[0] + soff) = vl;
  }
  __syncthreads();

  // this lane's C-rows: chunk sq, batch b, 4 state cols
  const int sq   = 2 * c2 + (br >> 3);
  const int b    = br & 7;
  const int col0 = w * 16 + akg * 4;
  int rdoff[8];
  #pragma unroll
  for (int s = 0; s < 8; ++s)
    rdoff[s] = (s << 10) + ((((akg << 4) | br) ^ s) << 4);
  const int sw    = col0 >> 5;
  const int akr   = (col0 >> 3) & 3;
  const int wroff = (sw << 10) + ((((akr << 4) | br) ^ sw) << 4) + (col0 & 7) * 2;

  f32x4 res;
  int q = 0, p = 0;
  #pragma unroll 1
  for (int j = 0; j < CHUNK; ++j) {
    float4 xn;
    if (j + 1 < CHUNK) xn = *(const float4*)(xsrc + (size_t)(j + 1) * ND);
    // B-chain: u = x_j @ B
    f32x4 accm = (f32x4)0.0f, acclA = (f32x4)0.0f, acclB = (f32x4)0.0f;
    {
      const char* rH = (const char*)xH[q];
      const char* rL = (const char*)xL[q];
      #pragma unroll
      for (int s = 0; s < 8; ++s) {
        const f16x8 bh = *(const f16x8*)(rH + rdoff[s]);
        const f16x8 bl = *(const f16x8*)(rL + rdoff[s]);
        accm  = __builtin_amdgcn_mfma_f32_16x16x32_f16(BH[s], bh, accm,  0, 0, 0);
        acclA = __builtin_amdgcn_mfma_f32_16x16x32_f16(BL[s], bh, acclA, 0, 0, 0);
        acclB = __builtin_amdgcn_mfma_f32_16x16x32_f16(BH[s], bl, acclB, 0, 0, 0);
      }
    }
    // snapshot u -> U (pass-1 input)
    {
      float4 o;
      o.x = accm[0] + (acclA[0] + acclB[0]) * LOINV;
      o.y = accm[1] + (acclA[1] + acclB[1]) * LOINV;
      o.z = accm[2] + (acclA[2] + acclB[2]) * LOINV;
      o.w = accm[3] + (acclA[3] + acclB[3]) * LOINV;
      *(float4*)&U[((size_t)(sq * CHUNK + j) * NBATCH + b) * ND + col0] = o;
    }
    // A-chain: + h_{j-1} @ A  (h_{-1}=0)
    if (j > 0) {
      const char* rH = (const char*)hH[p];
      const char* rL = (const char*)hL[p];
      #pragma unroll
      for (int s = 0; s < 8; ++s) {
        const f16x8 bh = *(const f16x8*)(rH + rdoff[s]);
        const f16x8 bl = *(const f16x8*)(rL + rdoff[s]);
        accm  = __builtin_amdgcn_mfma_f32_16x16x32_f16(AH[s], bh, accm,  0, 0, 0);
        acclA = __builtin_amdgcn_mfma_f32_16x16x32_f16(AL[s], bh, acclA, 0, 0, 0);
        acclB = __builtin_amdgcn_mfma_f32_16x16x32_f16(AH[s], bl, acclB, 0, 0, 0);
      }
    }
    #pragma unroll
    for (int r = 0; r < 4; ++r) res[r] = accm[r] + (acclA[r] + acclB[r]) * LOINV;
    // write h_j -> hbuf[p^1]
    {
      f16x4 vh, vl;
      #pragma unroll
      for (int r = 0; r < 4; ++r) {
        const fp16_t hh = (fp16_t)res[r];
        vh[r] = hh;
        vl[r] = (fp16_t)((res[r] - (float)hh) * LOSC);
      }
      *(f16x4*)((char*)hH[p ^ 1] + wroff) = vh;
      *(f16x4*)((char*)hL[p ^ 1] + wroff) = vl;
    }
    // write x_{j+1} -> xbuf[q^1]
    if (j + 1 < CHUNK) {
      const float a[4] = {xn.x, xn.y, xn.z, xn.w};
      f16x4 vh, vl;
      #pragma unroll
      for (int r = 0; r < 4; ++r) {
        const fp16_t h = (fp16_t)a[r];
        vh[r] = h;
        vl[r] = (fp16_t)((a[r] - (float)h) * LOSC);
      }
      *(f16x4*)((char*)xH[q ^ 1] + soff) = vh;
      *(f16x4*)((char*)xL[q ^ 1] + soff) = vl;
    }
    q ^= 1; p ^= 1;
    __syncthreads();
  }
  // chunk-end state
  {
    float4 o;
    o.x = res[0]; o.y = res[1]; o.z = res[2]; o.w = res[3];
    *(float4*)&E[((size_t)sq * NBATCH + b) * ND + col0] = o;
  }
}

// ---------- fused down-sweep: scan from entry state; y = h@C emitted directly ----------
__global__ __launch_bounds__(1024, 1) void scan_down(
    const fp16_t* __restrict__ fAh, const fp16_t* __restrict__ fAl,
    const fp16_t* __restrict__ fCh, const fp16_t* __restrict__ fCl,
    const float* __restrict__ Hc, const float* __restrict__ U,
    float* __restrict__ y) {
  const int c2   = blockIdx.x;
  const int tid  = threadIdx.x;
  const int lane = tid & 63;
  const int w    = tid >> 6;
  const int br   = lane & 15;
  const int akg  = lane >> 4;

  __shared__ fp16_t hH[2][8 * 512], hL[2][8 * 512];

  // init hbuf[0] = entry states Hc
  {
    const int srow  = tid >> 6;
    const int scol  = (tid & 63) * 4;
    const int ss    = (tid >> 3) & 7;
    const int sak   = (tid >> 1) & 3;
    const int shalf = tid & 1;
    const int soff  = (ss << 10) + ((((sak << 4) | srow) ^ ss) << 4) + shalf * 8;
    const int sc = 2 * c2 + (srow >> 3);
    const int sb = srow & 7;
    const float4 v = *(const float4*)&Hc[((size_t)sc * NBATCH + sb) * ND + scol];
    const float a[4] = {v.x, v.y, v.z, v.w};
    f16x4 vh, vl;
    #pragma unroll
    for (int r = 0; r < 4; ++r) {
      const fp16_t h = (fp16_t)a[r];
      vh[r] = h;
      vl[r] = (fp16_t)((a[r] - (float)h) * LOSC);
    }
    *(f16x4*)((char*)hH[0] + soff) = vh;
    *(f16x4*)((char*)hL[0] + soff) = vl;
  }

  // resident frags: A^T and C^T
  f16x8 AH[8], AL[8], CH[8], CL[8];
  #pragma unroll
  for (int s = 0; s < 8; ++s) {
    const size_t fo = (((size_t)w * 8 + s) * 64 + lane) * 8;
    AH[s] = *(const f16x8*)&fAh[fo];
    AL[s] = *(const f16x8*)&fAl[fo];
    CH[s] = *(const f16x8*)&fCh[fo];
    CL[s] = *(const f16x8*)&fCl[fo];
  }
  __syncthreads();

  const int sq   = 2 * c2 + (br >> 3);
  const int b    = br & 7;
  const int col0 = w * 16 + akg * 4;
  int rdoff[8];
  #pragma unroll
  for (int s = 0; s < 8; ++s)
    rdoff[s] = (s << 10) + ((((akg << 4) | br) ^ s) << 4);
  const int sw    = col0 >> 5;
  const int akr   = (col0 >> 3) & 3;
  const int wroff = (sw << 10) + ((((akr << 4) | br) ^ sw) << 4) + (col0 & 7) * 2;
  const size_t t0 = (size_t)sq * CHUNK;

  float4 uv = *(const float4*)&U[(t0 * NBATCH + b) * ND + col0];
  float4 uvn;
  f32x4 res;
  int p = 0;

  // j = 0: h_0 = entry@A + u_0  (no y yet)
  {
    uvn = *(const float4*)&U[((t0 + 1) * NBATCH + b) * ND + col0];
    f32x4 accm, acclA = (f32x4)0.0f, acclB = (f32x4)0.0f;
    accm[0] = uv.x; accm[1] = uv.y; accm[2] = uv.z; accm[3] = uv.w;
    const char* rH = (const char*)hH[0];
    const char* rL = (const char*)hL[0];
    #pragma unroll
    for (int s = 0; s < 8; ++s) {
      const f16x8 bh = *(const f16x8*)(rH + rdoff[s]);
      const f16x8 bl = *(const f16x8*)(rL + rdoff[s]);
      accm  = __builtin_amdgcn_mfma_f32_16x16x32_f16(AH[s], bh, accm,  0, 0, 0);
      acclA = __builtin_amdgcn_mfma_f32_16x16x32_f16(AL[s], bh, acclA, 0, 0, 0);
      acclB = __builtin_amdgcn_mfma_f32_16x16x32_f16(AH[s], bl, acclB, 0, 0, 0);
    }
    #pragma unroll
    for (int r = 0; r < 4; ++r) res[r] = accm[r] + (acclA[r] + acclB[r]) * LOINV;
    f16x4 vh, vl;
    #pragma unroll
    for (int r = 0; r < 4; ++r) {
      const fp16_t hh = (fp16_t)res[r];
      vh[r] = hh;
      vl[r] = (fp16_t)((res[r] - (float)hh) * LOSC);
    }
    *(f16x4*)((char*)hH[1] + wroff) = vh;
    *(f16x4*)((char*)hL[1] + wroff) = vl;
    uv = uvn;
    p = 1;
    __syncthreads();
  }

  // j = 1..7: h_j = h_{j-1}@A + u_j  AND  y_{j-1} = h_{j-1}@C (same frag reads)
  #pragma unroll 1
  for (int j = 1; j < CHUNK; ++j) {
    if (j + 1 < CHUNK)
      uvn = *(const float4*)&U[((t0 + j + 1) * NBATCH + b) * ND + col0];
    f32x4 am, alA = (f32x4)0.0f, alB = (f32x4)0.0f;
    f32x4 cm = (f32x4)0.0f, clA = (f32x4)0.0f, clB = (f32x4)0.0f;
    am[0] = uv.x; am[1] = uv.y; am[2] = uv.z; am[3] = uv.w;
    const char* rH = (const char*)hH[p];
    const char* rL = (const char*)hL[p];
    #pragma unroll
    for (int s = 0; s < 8; ++s) {
      const f16x8 bh = *(const f16x8*)(rH + rdoff[s]);
      const f16x8 bl = *(const f16x8*)(rL + rdoff[s]);
      am  = __builtin_amdgcn_mfma_f32_16x16x32_f16(AH[s], bh, am,  0, 0, 0);
      alA = __builtin_amdgcn_mfma_f32_16x16x32_f16(AL[s], bh, alA, 0, 0, 0);
      alB = __builtin_amdgcn_mfma_f32_16x16x32_f16(AH[s], bl, alB, 0, 0, 0);
      cm  = __builtin_amdgcn_mfma_f32_16x16x32_f16(CH[s], bh, cm,  0, 0, 0);
      clA = __builtin_amdgcn_mfma_f32_16x16x32_f16(CL[s], bh, clA, 0, 0, 0);
      clB = __builtin_amdgcn_mfma_f32_16x16x32_f16(CH[s], bl, clB, 0, 0, 0);
    }
    #pragma unroll
    for (int r = 0; r < 4; ++r) res[r] = am[r] + (alA[r] + alB[r]) * LOINV;
    {
      f16x4 vh, vl;
      #pragma unroll
      for (int r = 0; r < 4; ++r) {
        const fp16_t hh = (fp16_t)res[r];
        vh[r] = hh;
        vl[r] = (fp16_t)((res[r] - (float)hh) * LOSC);
      }
      *(f16x4*)((char*)hH[p ^ 1] + wroff) = vh;
      *(f16x4*)((char*)hL[p ^ 1] + wroff) = vl;
    }
    {
      float4 o;
      o.x = cm[0] + (clA[0] + clB[0]) * LOINV;
      o.y = cm[1] + (clA[1] + clB[1]) * LOINV;
      o.z = cm[2] + (clA[2] + clB[2]) * LOINV;
      o.w = cm[3] + (clA[3] + clB[3]) * LOINV;
      *(float4*)&y[((size_t)b * SEQ + t0 + j - 1) * ND + col0] = o;
    }
    uv = uvn;
    p ^= 1;
    __syncthreads();
  }

  // epilogue: y_7 = h_7 @ C
  {
    f32x4 cm = (f32x4)0.0f, clA = (f32x4)0.0f, clB = (f32x4)0.0f;
    const char* rH = (const char*)hH[p];
    const char* rL = (const char*)hL[p];
    #pragma unroll
    for (int s = 0; s < 8; ++s) {
      const f16x8 bh = *(const f16x8*)(rH + rdoff[s]);
      const f16x8 bl = *(const f16x8*)(rL + rdoff[s]);
      cm  = __builtin_amdgcn_mfma_f32_16x16x32_f16(CH[s], bh, cm,  0, 0, 0);
      clA = __builtin_amdgcn_mfma_f32_16x16x32_f16(CL[s], bh, clA, 0, 0, 0);
      clB = __builtin_amdgcn_mfma_f32_16x16x32_f16(CH[s], bl, clB, 0, 0, 0);
    }
    float4 o;
    o.x = cm[0] + (clA[0] + clB[0]) * LOINV;
    o.y = cm[1] + (clA[1] + clB[1]) * LOINV;
    o.z = cm[2] + (clA[2] + clB[2]) * LOINV;
    o.w = cm[3] + (clA[3] + clB[3]) * LOINV;
    *(float4*)&y[((size_t)b * SEQ + t0 + CHUNK - 1) * ND + col0] = o;
  }
}

// ---------- unified MFMA recurrence kernel (spine levels) ----------
__global__ __launch_bounds__(1024, 2) void mfma_rscan(
    const fp16_t* __restrict__ Mh, const fp16_t* __restrict__ Ml,
    const float* __restrict__ Init,
    const float* In,
    float* OutEach,
    float* __restrict__ OutFinal,
    int nupd, int gstride, int nseq, int init_bcast, int entry_mode) {
  const int seq0 = blockIdx.x * 2;
  const int tid  = threadIdx.x;
  const int lane = tid & 63;
  const int w    = tid >> 6;
  const int br   = lane & 15;
  const int akg  = lane >> 4;

  __shared__ fp16_t hH[2][8 * 512];
  __shared__ fp16_t hL[2][8 * 512];

  {
    const int task = tid >> 1;
    const int half = tid & 1;
    const int row  = task & 15;
    const int s    = (task >> 4) & 7;
    const int ak   = task >> 7;
    const int sq = seq0 + (row >> 3);
    const int b  = row & 7;
    const int c0 = s * 32 + ak * 8 + half * 4;
    float4 v = make_float4(0.f, 0.f, 0.f, 0.f);
    if (Init != nullptr && sq < nseq) {
      const size_t off = init_bcast ? (size_t)c0
                                    : ((size_t)sq * NBATCH + b) * ND + c0;
      v = *(const float4*)&Init[off];
      if (entry_mode && OutEach != nullptr)
        *(float4*)&OutEach[((size_t)sq * gstride * NBATCH + b) * ND + c0] = v;
    }
    const float a[4] = {v.x, v.y, v.z, v.w};
    f16x4 vh, vl;
    #pragma unroll
    for (int j = 0; j < 4; ++j) {
      const fp16_t h = (fp16_t)a[j];
      vh[j] = h;
      vl[j] = (fp16_t)((a[j] - (float)h) * LOSC);
    }
    const int off = (s << 10) + ((((ak << 4) | row) ^ s) << 4) + half * 8;
    *(f16x4*)((char*)hH[0] + off) = vh;
    *(f16x4*)((char*)hL[0] + off) = vl;
  }

  f16x8 AH[8], AL[8];
  #pragma unroll
  for (int s = 0; s < 8; ++s) {
    const size_t fo = (((size_t)w * 8 + s) * 64 + lane) * 8;
    AH[s] = *(const f16x8*)&Mh[fo];
    AL[s] = *(const f16x8*)&Ml[fo];
  }
  __syncthreads();

  const int sq   = seq0 + (br >> 3);
  const int b    = br & 7;
  const bool live = (sq < nseq);
  const int sqc  = live ? sq : (nseq - 1);
  const int col0 = w * 16 + akg * 4;

  int rdoff[8];
  #pragma unroll
  for (int s = 0; s < 8; ++s)
    rdoff[s] = (s << 10) + ((((akg << 4) | br) ^ s) << 4);
  const int sw   = col0 >> 5;
  const int akr  = (col0 >> 3) & 3;
  const int wroff = (sw << 10) + ((((akr << 4) | br) ^ sw) << 4) + (col0 & 7) * 2;

  float4 uv = *(const float4*)&In[((size_t)(sqc * gstride) * NBATCH + b) * ND + col0];
  float4 uvn;
  f32x4 res;
  int p = 0;
  for (int j = 0; j < nupd; ++j) {
    if (j + 1 < nupd)
      uvn = *(const float4*)&In[((size_t)(sqc * gstride + j + 1) * NBATCH + b) * ND + col0];
    const char* rH = (const char*)hH[p];
    const char* rL = (const char*)hL[p];
    f32x4 accm, acclA, acclB;
    accm[0] = uv.x; accm[1] = uv.y; accm[2] = uv.z; accm[3] = uv.w;
    acclA = (f32x4)0.0f;
    acclB = (f32x4)0.0f;
    #pragma unroll
    for (int s = 0; s < 8; ++s) {
      const f16x8 bh = *(const f16x8*)(rH + rdoff[s]);
      const f16x8 bl = *(const f16x8*)(rL + rdoff[s]);
      accm  = __builtin_amdgcn_mfma_f32_16x16x32_f16(AH[s], bh, accm,  0, 0, 0);
      acclA = __builtin_amdgcn_mfma_f32_16x16x32_f16(AL[s], bh, acclA, 0, 0, 0);
      acclB = __builtin_amdgcn_mfma_f32_16x16x32_f16(AH[s], bl, acclB, 0, 0, 0);
    }
    #pragma unroll
    for (int r = 0; r < 4; ++r) res[r] = accm[r] + (acclA[r] + acclB[r]) * LOINV;
    {
      f16x4 vh, vl;
      #pragma unroll
      for (int r = 0; r < 4; ++r) {
        const fp16_t hh = (fp16_t)res[r];
        vh[r] = hh;
        vl[r] = (fp16_t)((res[r] - (float)hh) * LOSC);
      }
      *(f16x4*)((char*)hH[p ^ 1] + wroff) = vh;
      *(f16x4*)((char*)hL[p ^ 1] + wroff) = vl;
    }
    if (OutEach != nullptr && live) {
      const size_t pos = entry_mode ? (size_t)(sq * gstride + j + 1)
                                    : (size_t)(sq * gstride + j);
      float4 o;
      o.x = res[0]; o.y = res[1]; o.z = res[2]; o.w = res[3];
      *(float4*)&OutEach[(pos * NBATCH + b) * ND + col0] = o;
    }
    uv = uvn;
    p ^= 1;
    __syncthreads();
  }

  if (OutFinal != nullptr && live) {
    float4 o;
    o.x = res[0]; o.y = res[1]; o.z = res[2]; o.w = res[3];
    *(float4*)&OutFinal[((size_t)sq * NBATCH + b) * ND + col0] = o;
  }
}

// ---------- dense 256x256 f32 GEMM (A-power chain) ----------
__global__ __launch_bounds__(256) void gemm256(const float* __restrict__ X,
                                               const float* __restrict__ Y,
                                               float* __restrict__ Out) {
  const int m0 = blockIdx.x * 4;
  const int n  = threadIdx.x;
  __shared__ float Xs[ND][4];
  #pragma unroll
  for (int r = 0; r < 4; ++r) Xs[n][r] = X[(m0 + r) * ND + n];
  __syncthreads();
  float a0 = 0.f, a1 = 0.f, a2 = 0.f, a3 = 0.f;
  #pragma unroll 8
  for (int k = 0; k < ND; ++k) {
    const float yv = Y[k * ND + n];
    const float4 xv = *(const float4*)&Xs[k][0];
    a0 = fmaf(xv.x, yv, a0);
    a1 = fmaf(xv.y, yv, a1);
    a2 = fmaf(xv.z, yv, a2);
    a3 = fmaf(xv.w, yv, a3);
  }
  Out[(m0 + 0) * ND + n] = a0;
  Out[(m0 + 1) * ND + n] = a1;
  Out[(m0 + 2) * ND + n] = a2;
  Out[(m0 + 3) * ND + n] = a3;
}

extern "C" void kernel_launch(void* const* d_in, const int* in_sizes, int n_in,
                              void* d_out, int out_size, void* d_ws, size_t ws_size,
                              hipStream_t stream) {
  const float* x  = (const float*)d_in[0];
  const float* A  = (const float*)d_in[1];
  const float* Bm = (const float*)d_in[2];
  const float* Cm = (const float*)d_in[3];
  const float* h0 = (const float*)d_in[4];
  float* y = (float*)d_out;

  float* U    = (float*)d_ws;                        // 8,388,608
  float* t0   = U + (size_t)SEQ * NBATCH * ND;       // 65,536 (reused for A8 frags)
  float* t1   = t0 + ND * ND;                        // 65,536 (reused for A128 frags)
  float* A8   = t1 + ND * ND;
  float* A128 = A8 + ND * ND;
  float* E    = A128 + ND * ND;                      // 1,048,576
  float* Sg   = E + (size_t)NCHUNK * NBATCH * ND;    // 65,536
  float* G    = Sg + (size_t)NGRP * NBATCH * ND;     // 65,536
  float* Hc   = G + (size_t)NGRP * NBATCH * ND;      // 1,048,576
  fp16_t* fA_hi = (fp16_t*)(Hc + (size_t)NCHUNK * NBATCH * ND);
  fp16_t* fA_lo = fA_hi + ND * ND;
  fp16_t* fB_hi = fA_lo + ND * ND;
  fp16_t* fB_lo = fB_hi + ND * ND;
  fp16_t* fC_hi = fB_lo + ND * ND;
  fp16_t* fC_lo = fC_hi + ND * ND;
  fp16_t* fA8_hi   = (fp16_t*)t0;
  fp16_t* fA8_lo   = fA8_hi + ND * ND;
  fp16_t* fA128_hi = (fp16_t*)t1;
  fp16_t* fA128_lo = fA128_hi + ND * ND;

  // pack A,B,C into fragment arrays
  prep_frags3<<<384, 64, 0, stream>>>(A, Bm, Cm, fA_hi, fA_lo, fB_hi, fB_lo,
                                      fC_hi, fC_lo);

  // A powers (f32): A^8, A^128  (t0/t1 scratch, then freed)
  gemm256<<<64, 256, 0, stream>>>(A,  A,  t0);       // A^2
  gemm256<<<64, 256, 0, stream>>>(t0, t0, t1);       // A^4
  gemm256<<<64, 256, 0, stream>>>(t1, t1, A8);       // A^8
  gemm256<<<64, 256, 0, stream>>>(A8, A8, t0);       // A^16
  gemm256<<<64, 256, 0, stream>>>(t0, t0, t1);       // A^32
  gemm256<<<64, 256, 0, stream>>>(t1, t1, t0);       // A^64
  gemm256<<<64, 256, 0, stream>>>(t0, t0, A128);     // A^128

  // pack A8/A128 into frags (t0/t1 storage reuse)
  prep_frags2<<<256, 64, 0, stream>>>(A8, A128, fA8_hi, fA8_lo,
                                      fA128_hi, fA128_lo);

  // fused up-sweep: u=x@B on the fly; chunk local scan -> U, E
  scan_up<<<NCHUNK / 2, 1024, 0, stream>>>(fA_hi, fA_lo, fB_hi, fB_lo, x, U, E);

  // group collect: Sg[g] = scan(0; E over group g) with A^8
  mfma_rscan<<<NGRP / 2, 1024, 0, stream>>>(fA8_hi, fA8_lo, nullptr, E,
                                            nullptr, Sg, GSZ, GSZ, NGRP, 0, 0);

  // top scan: G[0]=h0; G[g+1] = G[g]@A128 + Sg[g]
  mfma_rscan<<<1, 1024, 0, stream>>>(fA128_hi, fA128_lo, h0, Sg,
                                     G, nullptr, NGRP - 1, NGRP, 1, 1, 1);

  // group entries: Hc[g*GSZ]=G[g]; Hc[c+1] = Hc[c]@A8 + E[c]
  mfma_rscan<<<NGRP / 2, 1024, 0, stream>>>(fA8_hi, fA8_lo, G, E,
                                            Hc, nullptr, GSZ - 1, GSZ, NGRP,
                                            0, 1);

  // fused down-sweep: chunk scan from entry + y = h@C
  scan_down<<<NCHUNK / 2, 1024, 0, stream>>>(fA_hi, fA_lo, fC_hi, fC_lo,
                                             Hc, U, y);
}

// Round 9
// 248.400 us; speedup vs baseline: 1.2884x; 1.2884x over previous
//
#include <hip/hip_runtime.h>

// Linear RNN scan: h_t = h_{t-1}@A + x_t@B ; y_t = h_t@C
// B=8, S=4096, IN=STATE=OUT=256.
// MFMA 16x16x32 f16, 2-term split (hi + 2048*lo), f32 accumulate.
// Swapped operands: out^T = M^T @ in^T (frags = A-operand, LDS tile = B-operand).
// Slice-linear LDS: per slice s a 1024B region, slot ((ak<<4)|row)^s -> conflict-free.
// UNFUSED (round-7 structure): xb-gemm / chunk pass0 / spine / chunk pass1 / y-gemm.
// This round: __launch_bounds__(1024,4) to allow 128 VGPR (A-frags resident),
// and non-temporal hints on streaming traffic so frag arrays stay L2-resident.

#define SEQ    4096
#define NBATCH 8
#define ND     256
#define CHUNK  8
#define NCHUNK 512
#define GSZ    16
#define NGRP   32
#define LOSC   2048.0f
#define LOINV  (1.0f/2048.0f)

typedef _Float16 fp16_t;
typedef __attribute__((ext_vector_type(8))) _Float16 f16x8;
typedef __attribute__((ext_vector_type(4))) _Float16 f16x4;
typedef __attribute__((ext_vector_type(4))) float f32x4;

// non-temporal streaming helpers (keep L2 for the frag arrays)
__device__ __forceinline__ f32x4 ldnt4(const float* p) {
  return __builtin_nontemporal_load((const f32x4*)p);
}
__device__ __forceinline__ void stnt4(float* p, f32x4 v) {
  __builtin_nontemporal_store(v, (f32x4*)p);
}

// ---------- pack A,B,C into frag arrays (hi/lo f16) ----------
// frag linear index: ((tile*8 + slice)*64 + lane)*8 + j
// value = M[k][n], k = slice*32 + (lane>>4)*8 + j, n = tile*16 + (lane&15)
__global__ __launch_bounds__(64) void prep_frags3(
    const float* __restrict__ A, const float* __restrict__ B,
    const float* __restrict__ C,
    fp16_t* __restrict__ fAh, fp16_t* __restrict__ fAl,
    fp16_t* __restrict__ fBh, fp16_t* __restrict__ fBl,
    fp16_t* __restrict__ fCh, fp16_t* __restrict__ fCl) {
  const int which = blockIdx.x >> 7;
  const int blk   = blockIdx.x & 127;
  const float* M = (which == 0) ? A : (which == 1) ? B : C;
  fp16_t* hi = (which == 0) ? fAh : (which == 1) ? fBh : fCh;
  fp16_t* lo = (which == 0) ? fAl : (which == 1) ? fBl : fCl;
  const int lane = threadIdx.x;
  const int tile = blk >> 3, slice = blk & 7;
  const int n  = tile * 16 + (lane & 15);
  const int k0 = slice * 32 + (lane >> 4) * 8;
  f16x8 vh, vl;
  #pragma unroll
  for (int j = 0; j < 8; ++j) {
    const float v = M[(size_t)(k0 + j) * ND + n];
    const fp16_t h = (fp16_t)v;
    vh[j] = h;
    vl[j] = (fp16_t)((v - (float)h) * LOSC);
  }
  const size_t fo = ((size_t)blk * 64 + lane) * 8;
  *(f16x8*)&hi[fo] = vh;
  *(f16x8*)&lo[fo] = vl;
}

// ---------- pack A8, A128 into frag arrays ----------
__global__ __launch_bounds__(64) void prep_frags2(
    const float* __restrict__ M0, const float* __restrict__ M1,
    fp16_t* __restrict__ h0p, fp16_t* __restrict__ l0p,
    fp16_t* __restrict__ h1p, fp16_t* __restrict__ l1p) {
  const int which = blockIdx.x >> 7;
  const int blk   = blockIdx.x & 127;
  const float* M = (which == 0) ? M0 : M1;
  fp16_t* hi = (which == 0) ? h0p : h1p;
  fp16_t* lo = (which == 0) ? l0p : l1p;
  const int lane = threadIdx.x;
  const int tile = blk >> 3, slice = blk & 7;
  const int n  = tile * 16 + (lane & 15);
  const int k0 = slice * 32 + (lane >> 4) * 8;
  f16x8 vh, vl;
  #pragma unroll
  for (int j = 0; j < 8; ++j) {
    const float v = M[(size_t)(k0 + j) * ND + n];
    const fp16_t h = (fp16_t)v;
    vh[j] = h;
    vl[j] = (fp16_t)((v - (float)h) * LOSC);
  }
  const size_t fo = ((size_t)blk * 64 + lane) * 8;
  *(f16x8*)&hi[fo] = vh;
  *(f16x8*)&lo[fo] = vl;
}

// ---------- MFMA GEMM: Out[m][:] = X[m][:] @ M,  m = s*8+b, M-block = 64 ----------
// mode 0 (xb): X rows remapped from x[b][s][:];  mode 1 (y): Out remapped to y[b][s][:]
__global__ __launch_bounds__(1024, 4) void mfma_gemm(const float* __restrict__ X,
                                                     const fp16_t* __restrict__ Mhi,
                                                     const fp16_t* __restrict__ Mlo,
                                                     float* __restrict__ Out,
                                                     int mode) {
  const int m0   = blockIdx.x * 64;
  const int tid  = threadIdx.x;
  const int lane = tid & 63;
  const int w    = tid >> 6;          // 16 waves, M-col tile w
  const int br   = lane & 15;
  const int akg  = lane >> 4;

  __shared__ fp16_t Xh[32 * 512];     // 32 regions x 1024B (slice-linear)
  __shared__ fp16_t Xl[32 * 512];
  char* Xhb = (char*)Xh;
  char* Xlb = (char*)Xl;

  // stage 64 rows of X -> hi/lo, slice-linear layout (fully coalesced global, NT)
  #pragma unroll
  for (int pass = 0; pass < 2; ++pass) {
    const int tau = pass * 1024 + tid;
    const int row = tau >> 5;         // 0..63
    const int sub = tau & 31;
    const int s   = sub >> 2;
    const int ak  = sub & 3;
    const int m = m0 + row;
    const size_t in_row = (mode == 0)
        ? ((size_t)(m & 7) * SEQ + (m >> 3))
        : (size_t)m;
    const float* xp = &X[in_row * ND + s * 32 + ak * 8];
    const f32x4 x0 = ldnt4(xp);
    const f32x4 x1 = ldnt4(xp + 4);
    const float a[8] = {x0[0], x0[1], x0[2], x0[3], x1[0], x1[1], x1[2], x1[3]};
    f16x8 vh, vl;
    #pragma unroll
    for (int j = 0; j < 8; ++j) {
      const fp16_t h = (fp16_t)a[j];
      vh[j] = h;
      vl[j] = (fp16_t)((a[j] - (float)h) * LOSC);
    }
    const int off = (((row >> 4) * 8 + s) << 10) +
                    (((ak << 4) | (row & 15)) ^ s) * 16;
    *(f16x8*)(Xhb + off) = vh;
    *(f16x8*)(Xlb + off) = vl;
  }

  // resident M^T frags (A-operand) for this wave's M-col tile
  f16x8 MH[8], ML[8];
  #pragma unroll
  for (int s = 0; s < 8; ++s) {
    const size_t fo = (((size_t)w * 8 + s) * 64 + lane) * 8;
    MH[s] = *(const f16x8*)&Mhi[fo];
    ML[s] = *(const f16x8*)&Mlo[fo];
  }
  __syncthreads();

  f32x4 accm[4], accl[4];
  #pragma unroll
  for (int mt = 0; mt < 4; ++mt) {
    accm[mt] = (f32x4)0.0f;
    accl[mt] = (f32x4)0.0f;
  }

  #pragma unroll
  for (int s = 0; s < 8; ++s) {
    #pragma unroll
    for (int mt = 0; mt < 4; ++mt) {
      const int byte = ((mt * 8 + s) << 10) + ((((akg << 4) | br) ^ s) << 4);
      const f16x8 bh = *(const f16x8*)(Xhb + byte);
      const f16x8 bl = *(const f16x8*)(Xlb + byte);
      accm[mt] = __builtin_amdgcn_mfma_f32_16x16x32_f16(MH[s], bh, accm[mt], 0, 0, 0);
      accl[mt] = __builtin_amdgcn_mfma_f32_16x16x32_f16(ML[s], bh, accl[mt], 0, 0, 0);
      accl[mt] = __builtin_amdgcn_mfma_f32_16x16x32_f16(MH[s], bl, accl[mt], 0, 0, 0);
    }
  }

  #pragma unroll
  for (int mt = 0; mt < 4; ++mt) {
    const int m = m0 + mt * 16 + br;            // output row (X-row)
    const size_t out_row = (mode == 1)
        ? ((size_t)(m & 7) * SEQ + (m >> 3))
        : (size_t)m;
    f32x4 o;
    #pragma unroll
    for (int r = 0; r < 4; ++r) o[r] = accm[mt][r] + accl[mt][r] * LOINV;
    stnt4(&Out[out_row * ND + w * 16 + akg * 4], o);
  }
}

// ---------- unified MFMA recurrence kernel (swapped operands) ----------
// Each block runs TWO independent 8-row sequences (seq = blockIdx.x*2 + rowgrp).
// For nupd steps: h = h @ Mult + In[(seq*gstride + j)*NB + b].
// Init: null -> zero; init_bcast -> Init[col]; else Init[(seq*NB+b)*ND+col].
// entry_mode=0: OutEach written at (seq*gstride + j).
// entry_mode=1: OutEach gets Init at (seq*gstride), step-j state at (.. + j + 1).
// OutFinal: final state at row (seq*NB+b).
__global__ __launch_bounds__(1024, 4) void mfma_rscan(
    const fp16_t* __restrict__ Mh, const fp16_t* __restrict__ Ml,
    const float* __restrict__ Init,
    const float* In,
    float* OutEach,
    float* __restrict__ OutFinal,
    int nupd, int gstride, int nseq, int init_bcast, int entry_mode) {
  const int seq0 = blockIdx.x * 2;
  const int tid  = threadIdx.x;
  const int lane = tid & 63;
  const int w    = tid >> 6;          // 16 waves, state-col tile w
  const int br   = lane & 15;         // batch row 0..15
  const int akg  = lane >> 4;

  __shared__ fp16_t hH[2][8 * 512];   // [buf][slice-linear 8KB]
  __shared__ fp16_t hL[2][8 * 512];

  // init h (buf 0), slice-linear
  {
    const int task = tid >> 1;        // 0..511
    const int half = tid & 1;
    const int row  = task & 15;
    const int s    = (task >> 4) & 7;
    const int ak   = task >> 7;       // 0..3
    const int sq = seq0 + (row >> 3);
    const int b  = row & 7;
    const int c0 = s * 32 + ak * 8 + half * 4;
    f32x4 v = (f32x4)0.0f;
    if (Init != nullptr && sq < nseq) {
      const size_t off = init_bcast ? (size_t)c0
                                    : ((size_t)sq * NBATCH + b) * ND + c0;
      v = *(const f32x4*)&Init[off];
      if (entry_mode && OutEach != nullptr)
        stnt4(&OutEach[((size_t)sq * gstride * NBATCH + b) * ND + c0], v);
    }
    f16x4 vh, vl;
    #pragma unroll
    for (int j = 0; j < 4; ++j) {
      const fp16_t h = (fp16_t)v[j];
      vh[j] = h;
      vl[j] = (fp16_t)((v[j] - (float)h) * LOSC);
    }
    const int off = (s << 10) + ((((ak << 4) | row) ^ s) << 4) + half * 8;
    *(f16x4*)((char*)hH[0] + off) = vh;
    *(f16x4*)((char*)hL[0] + off) = vl;
  }

  // resident A^T frags (A-operand) for this wave's state-col tile
  f16x8 AH[8], AL[8];
  #pragma unroll
  for (int s = 0; s < 8; ++s) {
    const size_t fo = (((size_t)w * 8 + s) * 64 + lane) * 8;
    AH[s] = *(const f16x8*)&Mh[fo];
    AL[s] = *(const f16x8*)&Ml[fo];
  }
  __syncthreads();

  // this lane's output: batch-row br -> (seq, b); 4 consecutive state cols
  const int sq   = seq0 + (br >> 3);
  const int b    = br & 7;
  const bool live = (sq < nseq);
  const int sqc  = live ? sq : (nseq - 1);     // clamp for safe loads
  const int col0 = w * 16 + akg * 4;

  // precomputed LDS offsets
  int rdoff[8];
  #pragma unroll
  for (int s = 0; s < 8; ++s)
    rdoff[s] = (s << 10) + ((((akg << 4) | br) ^ s) << 4);
  const int sw   = col0 >> 5;
  const int akr  = (col0 >> 3) & 3;
  const int wroff = (sw << 10) + ((((akr << 4) | br) ^ sw) << 4) + (col0 & 7) * 2;

  f32x4 uv = ldnt4(&In[((size_t)(sqc * gstride) * NBATCH + b) * ND + col0]);
  f32x4 uvn;
  f32x4 res;
  int p = 0;
  for (int j = 0; j < nupd; ++j) {
    if (j + 1 < nupd)
      uvn = ldnt4(&In[((size_t)(sqc * gstride + j + 1) * NBATCH + b) * ND + col0]);
    const char* rH = (const char*)hH[p];
    const char* rL = (const char*)hL[p];
    f32x4 accm, acclA, acclB;
    accm = uv;
    acclA = (f32x4)0.0f;
    acclB = (f32x4)0.0f;
    #pragma unroll
    for (int s = 0; s < 8; ++s) {
      const f16x8 bh = *(const f16x8*)(rH + rdoff[s]);
      const f16x8 bl = *(const f16x8*)(rL + rdoff[s]);
      accm  = __builtin_amdgcn_mfma_f32_16x16x32_f16(AH[s], bh, accm,  0, 0, 0);
      acclA = __builtin_amdgcn_mfma_f32_16x16x32_f16(AL[s], bh, acclA, 0, 0, 0);
      acclB = __builtin_amdgcn_mfma_f32_16x16x32_f16(AH[s], bl, acclB, 0, 0, 0);
    }
    #pragma unroll
    for (int r = 0; r < 4; ++r) res[r] = accm[r] + (acclA[r] + acclB[r]) * LOINV;
    // write new h into the OTHER buffer (no barrier needed before writes)
    {
      f16x4 vh, vl;
      #pragma unroll
      for (int r = 0; r < 4; ++r) {
        const fp16_t hh = (fp16_t)res[r];
        vh[r] = hh;
        vl[r] = (fp16_t)((res[r] - (float)hh) * LOSC);
      }
      *(f16x4*)((char*)hH[p ^ 1] + wroff) = vh;
      *(f16x4*)((char*)hL[p ^ 1] + wroff) = vl;
    }
    if (OutEach != nullptr && live) {
      const size_t pos = entry_mode ? (size_t)(sq * gstride + j + 1)
                                    : (size_t)(sq * gstride + j);
      stnt4(&OutEach[(pos * NBATCH + b) * ND + col0], res);
    }
    uv = uvn;
    p ^= 1;
    __syncthreads();                  // new h visible; old buf free for reuse
  }

  if (OutFinal != nullptr && live) {
    f32x4 o = res;
    *(f32x4*)&OutFinal[((size_t)sq * NBATCH + b) * ND + col0] = o;
  }
}

// ---------- dense 256x256 f32 GEMM (A-power chain) ----------
__global__ __launch_bounds__(256) void gemm256(const float* __restrict__ X,
                                               const float* __restrict__ Y,
                                               float* __restrict__ Out) {
  const int m0 = blockIdx.x * 4;
  const int n  = threadIdx.x;
  __shared__ float Xs[ND][4];
  #pragma unroll
  for (int r = 0; r < 4; ++r) Xs[n][r] = X[(m0 + r) * ND + n];
  __syncthreads();
  float a0 = 0.f, a1 = 0.f, a2 = 0.f, a3 = 0.f;
  #pragma unroll 8
  for (int k = 0; k < ND; ++k) {
    const float yv = Y[k * ND + n];
    const float4 xv = *(const float4*)&Xs[k][0];
    a0 = fmaf(xv.x, yv, a0);
    a1 = fmaf(xv.y, yv, a1);
    a2 = fmaf(xv.z, yv, a2);
    a3 = fmaf(xv.w, yv, a3);
  }
  Out[(m0 + 0) * ND + n] = a0;
  Out[(m0 + 1) * ND + n] = a1;
  Out[(m0 + 2) * ND + n] = a2;
  Out[(m0 + 3) * ND + n] = a3;
}

extern "C" void kernel_launch(void* const* d_in, const int* in_sizes, int n_in,
                              void* d_out, int out_size, void* d_ws, size_t ws_size,
                              hipStream_t stream) {
  const float* x  = (const float*)d_in[0];
  const float* A  = (const float*)d_in[1];
  const float* Bm = (const float*)d_in[2];
  const float* Cm = (const float*)d_in[3];
  const float* h0 = (const float*)d_in[4];
  float* y = (float*)d_out;

  float* U    = (float*)d_ws;                        // 8,388,608
  float* t0   = U + (size_t)SEQ * NBATCH * ND;       // 65,536 (reused for A8 frags)
  float* t1   = t0 + ND * ND;                        // 65,536 (reused for A128 frags)
  float* A8   = t1 + ND * ND;
  float* A128 = A8 + ND * ND;
  float* E    = A128 + ND * ND;                      // 1,048,576
  float* Sg   = E + (size_t)NCHUNK * NBATCH * ND;    // 65,536
  float* G    = Sg + (size_t)NGRP * NBATCH * ND;     // 65,536
  float* Hc   = G + (size_t)NGRP * NBATCH * ND;      // 1,048,576
  fp16_t* fA_hi = (fp16_t*)(Hc + (size_t)NCHUNK * NBATCH * ND);
  fp16_t* fA_lo = fA_hi + ND * ND;
  fp16_t* fB_hi = fA_lo + ND * ND;
  fp16_t* fB_lo = fB_hi + ND * ND;
  fp16_t* fC_hi = fB_lo + ND * ND;
  fp16_t* fC_lo = fC_hi + ND * ND;
  fp16_t* fA8_hi   = (fp16_t*)t0;
  fp16_t* fA8_lo   = fA8_hi + ND * ND;
  fp16_t* fA128_hi = (fp16_t*)t1;
  fp16_t* fA128_lo = fA128_hi + ND * ND;

  // pack A,B,C into fragment arrays
  prep_frags3<<<384, 64, 0, stream>>>(A, Bm, Cm, fA_hi, fA_lo, fB_hi, fB_lo,
                                      fC_hi, fC_lo);

  // A powers (f32): A^8, A^128  (t0/t1 scratch, then freed)
  gemm256<<<64, 256, 0, stream>>>(A,  A,  t0);       // A^2
  gemm256<<<64, 256, 0, stream>>>(t0, t0, t1);       // A^4
  gemm256<<<64, 256, 0, stream>>>(t1, t1, A8);       // A^8
  gemm256<<<64, 256, 0, stream>>>(A8, A8, t0);       // A^16
  gemm256<<<64, 256, 0, stream>>>(t0, t0, t1);       // A^32
  gemm256<<<64, 256, 0, stream>>>(t1, t1, t0);       // A^64
  gemm256<<<64, 256, 0, stream>>>(t0, t0, A128);     // A^128

  // pack A8/A128 into frags (t0/t1 storage reuse)
  prep_frags2<<<256, 64, 0, stream>>>(A8, A128, fA8_hi, fA8_lo,
                                      fA128_hi, fA128_lo);

  // U = x @ B
  mfma_gemm<<<512, 1024, 0, stream>>>(x, fB_hi, fB_lo, U, 0);

  // chunk local ends: E[c] = scan(0; u over chunk c)
  mfma_rscan<<<NCHUNK / 2, 1024, 0, stream>>>(fA_hi, fA_lo, nullptr, U,
                                              nullptr, E, CHUNK, CHUNK,
                                              NCHUNK, 0, 0);

  // group collect: Sg[g] = scan(0; E over group g) with A^8
  mfma_rscan<<<NGRP / 2, 1024, 0, stream>>>(fA8_hi, fA8_lo, nullptr, E,
                                            nullptr, Sg, GSZ, GSZ, NGRP, 0, 0);

  // top scan: G[0]=h0; G[g+1] = G[g]@A128 + Sg[g]
  mfma_rscan<<<1, 1024, 0, stream>>>(fA128_hi, fA128_lo, h0, Sg,
                                     G, nullptr, NGRP - 1, NGRP, 1, 1, 1);

  // group entries: Hc[g*GSZ]=G[g]; Hc[c+1] = Hc[c]@A8 + E[c]
  mfma_rscan<<<NGRP / 2, 1024, 0, stream>>>(fA8_hi, fA8_lo, G, E,
                                            Hc, nullptr, GSZ - 1, GSZ, NGRP,
                                            0, 1);

  // final chunk scan from true entries; h overwrites U
  mfma_rscan<<<NCHUNK / 2, 1024, 0, stream>>>(fA_hi, fA_lo, Hc, U,
                                              U, nullptr, CHUNK, CHUNK,
                                              NCHUNK, 0, 0);

  // y = h @ C
  mfma_gemm<<<512, 1024, 0, stream>>>(U, fC_hi, fC_lo, y, 1);
}